// Round 1
// baseline (11698.898 us; speedup 1.0000x reference)
//
#include <hip/hip_runtime.h>

// RCNN forward, fp32 baseline.
// Pipeline: conv5x5(3->128,pad2) -> BN(batch stats) -> relu -> maxpool(3,2,1) 64->32
//   -> RCL(f2,r2) -> RCL(f3,r3) -> maxpool 32->16 -> RCL(f4,r4) -> RCL(f5,r5)
//   -> maxpool(3,2,0) 16->7 -> global max -> MLP(128->10)
// RCL(x): f = conv3x3(x)+b; r = LRN(relu(f)); 3x { r = LRN(relu(f + conv3x3(r))) }
// LRN: banded cross-channel, window 17 (+-8 clamped), out = z * (sum(z^2)*k+1)^-0.75

#define CCH 128
constexpr float KAPPA = 0.001f / 17.0f;

// ---------------------------------------------------------------- zero stats
__global__ __launch_bounds__(256) void zero_stats(float* __restrict__ s) {
    s[threadIdx.x] = 0.f;   // 256 floats: sum[128], sumsq[128]
}

// ------------------------------------------------- conv1 (5x5, 3->128) stats
// One block per (n, c). Stage padded x planes (3 x 68 x 72) in LDS, compute
// conv outputs for the 64x64 plane, reduce sum/sumsq, atomicAdd to stats.
__global__ __launch_bounds__(256) void conv1_stats(
    const float* __restrict__ x, const float* __restrict__ w,
    const float* __restrict__ bias, float* __restrict__ stats)
{
    __shared__ float xs[3 * 68 * 72];
    __shared__ float red[512];
    const int lid = blockIdx.x;                 // 16384 = 128n * 128c
    const int xcd = lid & 7, slot = lid >> 3;
    const int c = slot & 127;
    const int n = xcd + 8 * (slot >> 7);
    const int tid = threadIdx.x;

    const float* xn = x + (size_t)n * 3 * 4096;
    for (int idx = tid; idx < 3 * 68 * 72; idx += 256) {
        int ci = idx / 4896;
        int rem = idx - ci * 4896;
        int py = rem / 72;
        int px = rem - py * 72;
        int gy = py - 2, gx = px - 2;
        float v = 0.f;
        if ((unsigned)gy < 64u && (unsigned)gx < 64u)
            v = xn[ci * 4096 + gy * 64 + gx];
        xs[idx] = v;
    }
    __syncthreads();

    const float* wc = w + c * 75;
    const float bc = bias[c];
    float s = 0.f, s2 = 0.f;
    for (int g = tid; g < 1024; g += 256) {      // 4 groups of 4 x-pixels
        int y = g >> 4, x0 = (g & 15) * 4;
        float acc[4] = {bc, bc, bc, bc};
        #pragma unroll
        for (int ci = 0; ci < 3; ++ci)
            #pragma unroll
            for (int ky = 0; ky < 5; ++ky) {
                const float4* p = (const float4*)&xs[ci * 4896 + (y + ky) * 72 + x0];
                float4 a = p[0], b4 = p[1];
                float vv[8] = {a.x, a.y, a.z, a.w, b4.x, b4.y, b4.z, b4.w};
                #pragma unroll
                for (int kx = 0; kx < 5; ++kx) {
                    float wv = wc[ci * 25 + ky * 5 + kx];
                    #pragma unroll
                    for (int j = 0; j < 4; ++j) acc[j] += vv[j + kx] * wv;
                }
            }
        s  += acc[0] + acc[1] + acc[2] + acc[3];
        s2 += acc[0]*acc[0] + acc[1]*acc[1] + acc[2]*acc[2] + acc[3]*acc[3];
    }
    red[tid] = s; red[256 + tid] = s2;
    __syncthreads();
    for (int o = 128; o > 0; o >>= 1) {
        if (tid < o) { red[tid] += red[tid + o]; red[256 + tid] += red[256 + tid + o]; }
        __syncthreads();
    }
    if (tid == 0) { atomicAdd(&stats[c], red[0]); atomicAdd(&stats[c + 128], red[256]); }
}

// --------------------------------------------------------------- bn finalize
__global__ __launch_bounds__(128) void bn_finalize(
    const float* __restrict__ stats, const float* __restrict__ g,
    const float* __restrict__ b, float* __restrict__ scsh)
{
    const int c = threadIdx.x;
    const float M = 128.f * 4096.f;
    float mean = stats[c] / M;
    float var = stats[c + 128] / M - mean * mean;
    float rstd = rsqrtf(var + 1e-5f);
    float sc = g[c] * rstd;
    scsh[c] = sc;
    scsh[c + 128] = b[c] - mean * sc;
}

// ----------------------------------- conv1 + BN + relu + maxpool(3,2,1) 64->32
// One block per (n, c, half). Computes 33 h-rows (post BN+relu) in LDS, pools
// 16 output rows x 32 cols.
__global__ __launch_bounds__(256) void conv1_bn_pool(
    const float* __restrict__ x, const float* __restrict__ w,
    const float* __restrict__ bias, const float* __restrict__ scsh,
    float* __restrict__ out)
{
    __shared__ float xs[3 * 37 * 72];
    __shared__ float hs[33 * 65];
    const int lid = blockIdx.x;                 // 32768 = 128n * 128c * 2
    const int xcd = lid & 7, slot = lid >> 3;
    const int half = slot & 1;
    const int c = (slot >> 1) & 127;
    const int n = xcd + 8 * (slot >> 8);
    const int oy0 = half * 16;
    const int ybase = 2 * oy0 - 1;              // global y of hs row 0
    const int gybase = ybase - 2;               // global y of xs row 0
    const int tid = threadIdx.x;

    const float* xn = x + (size_t)n * 3 * 4096;
    for (int idx = tid; idx < 3 * 37 * 72; idx += 256) {
        int ci = idx / (37 * 72);
        int rem = idx - ci * (37 * 72);
        int ly = rem / 72;
        int px = rem - ly * 72;
        int gy = gybase + ly, gx = px - 2;
        float v = 0.f;
        if ((unsigned)gy < 64u && (unsigned)gx < 64u)
            v = xn[ci * 4096 + gy * 64 + gx];
        xs[idx] = v;
    }
    __syncthreads();

    const float* wc = w + c * 75;
    const float bc = bias[c];
    const float sc = scsh[c], sh = scsh[c + 128];
    for (int g = tid; g < 33 * 16; g += 256) {
        int hy = g >> 4, x0 = (g & 15) * 4;
        int ygl = ybase + hy;
        if ((unsigned)ygl < 64u) {
            float acc[4] = {bc, bc, bc, bc};
            #pragma unroll
            for (int ci = 0; ci < 3; ++ci)
                #pragma unroll
                for (int ky = 0; ky < 5; ++ky) {
                    const float4* p = (const float4*)&xs[ci * (37*72) + (hy + ky) * 72 + x0];
                    float4 a = p[0], b4 = p[1];
                    float vv[8] = {a.x, a.y, a.z, a.w, b4.x, b4.y, b4.z, b4.w};
                    #pragma unroll
                    for (int kx = 0; kx < 5; ++kx) {
                        float wv = wc[ci * 25 + ky * 5 + kx];
                        #pragma unroll
                        for (int j = 0; j < 4; ++j) acc[j] += vv[j + kx] * wv;
                    }
                }
            #pragma unroll
            for (int j = 0; j < 4; ++j)
                hs[hy * 65 + x0 + j] = fmaxf(acc[j] * sc + sh, 0.f);
        }
    }
    __syncthreads();

    float* ob = out + ((size_t)n * CCH + c) * 1024 + oy0 * 32;
    for (int p = tid; p < 512; p += 256) {
        int oyl = p >> 5, ox = p & 31;
        int oy = oy0 + oyl;
        float m = 0.f;                          // relu'd values are >= 0
        #pragma unroll
        for (int dy = -1; dy <= 1; ++dy) {
            int iy = 2 * oy + dy;
            if ((unsigned)iy >= 64u) continue;
            int hr = iy - ybase;
            #pragma unroll
            for (int dx = -1; dx <= 1; ++dx) {
                int ix = 2 * ox + dx;
                if ((unsigned)ix >= 64u) continue;
                m = fmaxf(m, hs[hr * 65 + ix]);
            }
        }
        ob[oyl * 32 + ox] = m;
    }
}

// --------------------------------------------- conv3x3 (128->128, pad 1)
// H=32: 4096 blocks = 128n * 32 co-groups(4 co); thread = (y, xg), 4co x 4x outs.
// H=16: 1024 blocks = 128n * 8 co-groups(16 co); thread = (co4, y, xg), 4co x 4x.
template<int H, bool BIAS>
__global__ __launch_bounds__(256) void conv3(
    const float* __restrict__ in, const float* __restrict__ w,
    const float* __restrict__ bias, float* __restrict__ out)
{
    constexpr int W = H, HW = H * W;
    constexpr int PH = H + 2;
    constexpr int PS = (H == 32) ? 36 : 20;      // padded row stride (16B aligned)
    constexpr int CHUNK = 8;
    constexpr int COPB = (H == 32) ? 4 : 16;     // co per block
    constexpr int COGB = (H == 32) ? 5 : 3;      // log2(#co groups)
    __shared__ float lds[CHUNK * PH * PS];

    const int lid = blockIdx.x;
    const int xcd = lid & 7, slot = lid >> 3;
    const int cog = slot & ((1 << COGB) - 1);
    const int n = xcd + 8 * (slot >> COGB);
    const int co0 = cog * COPB;
    const int tid = threadIdx.x;

    int y, x0, col0;
    if constexpr (H == 32) { y = tid >> 3; x0 = (tid & 7) * 4; col0 = 0; }
    else { y = (tid >> 2) & 15; x0 = (tid & 3) * 4; col0 = (tid >> 6) * 4; }

    float acc[4][4];
    #pragma unroll
    for (int a = 0; a < 4; ++a) {
        float bv = BIAS ? bias[co0 + col0 + a] : 0.f;
        #pragma unroll
        for (int j = 0; j < 4; ++j) acc[a][j] = bv;
    }

    const float* inb = in + (size_t)n * CCH * HW;
    for (int c0 = 0; c0 < CCH; c0 += CHUNK) {
        __syncthreads();
        for (int idx = tid; idx < CHUNK * PH * PS; idx += 256) {
            int ci_l = idx / (PH * PS);
            int rem = idx - ci_l * (PH * PS);
            int py = rem / PS;
            int px = rem - py * PS;
            int gy = py - 1, gx = px - 1;
            float v = 0.f;
            if ((unsigned)gy < (unsigned)H && (unsigned)gx < (unsigned)W)
                v = inb[(c0 + ci_l) * HW + gy * W + gx];
            lds[idx] = v;
        }
        __syncthreads();
        for (int ci_l = 0; ci_l < CHUNK; ++ci_l) {
            const int ci = c0 + ci_l;
            float vv[3][8];
            #pragma unroll
            for (int ky = 0; ky < 3; ++ky) {
                const float4* p = (const float4*)&lds[ci_l * (PH * PS) + (y + ky) * PS + x0];
                float4 a = p[0], b4 = p[1];
                vv[ky][0] = a.x; vv[ky][1] = a.y; vv[ky][2] = a.z; vv[ky][3] = a.w;
                vv[ky][4] = b4.x; vv[ky][5] = b4.y; vv[ky][6] = b4.z; vv[ky][7] = b4.w;
            }
            #pragma unroll
            for (int a = 0; a < 4; ++a) {
                const float* wr = w + ((size_t)(co0 + col0 + a) * CCH + ci) * 9;
                #pragma unroll
                for (int ky = 0; ky < 3; ++ky)
                    #pragma unroll
                    for (int kx = 0; kx < 3; ++kx) {
                        float wv = wr[ky * 3 + kx];
                        #pragma unroll
                        for (int j = 0; j < 4; ++j) acc[a][j] += vv[ky][j + kx] * wv;
                    }
            }
        }
    }
    #pragma unroll
    for (int a = 0; a < 4; ++a) {
        float4 o = {acc[a][0], acc[a][1], acc[a][2], acc[a][3]};
        *(float4*)&out[((size_t)n * CCH + co0 + col0 + a) * HW + y * W + x0] = o;
    }
}

// ------------------------------------------------------------------- LRN
// Streaming banded cross-channel normalization; one thread per (n, pixel).
// z = relu(f [+ t]); out = z * (wsum*k+1)^-0.75, wsum = window-17 sum of z^2.
template<int HW, bool HAS_T>
__global__ __launch_bounds__(256) void lrn_k(
    const float* __restrict__ f, const float* __restrict__ t, float* __restrict__ r)
{
    const int idx = blockIdx.x * 256 + threadIdx.x;   // n*HW + p
    const int n = idx / HW;
    const int p = idx - n * HW;
    const size_t base = (size_t)n * CCH * HW + p;
    const float* fb = f + base;
    const float* tb = HAS_T ? (t + base) : nullptr;
    float* rb = r + base;

    float ring[17];
    float zr[9];
    #pragma unroll
    for (int i = 0; i < 17; ++i) ring[i] = 0.f;
    #pragma unroll
    for (int i = 0; i < 9; ++i) zr[i] = 0.f;
    float wsum = 0.f;

    #pragma unroll
    for (int c = 0; c < CCH + 8; ++c) {
        float z = 0.f;
        if (c < CCH) {
            float v = fb[c * HW];
            if (HAS_T) v += tb[c * HW];
            z = v > 0.f ? v : 0.f;
        }
        float zz = z * z;
        wsum += zz - ring[c % 17];
        ring[c % 17] = zz;
        zr[c % 9] = z;
        if (c >= 8) {
            int o = c - 8;
            float arg = wsum * KAPPA + 1.f;
            float p75 = exp2f(-0.75f * log2f(arg));
            rb[o * HW] = zr[(c + 1) % 9] * p75;   // zr slot of z[c-8]
        }
    }
}

// -------------------------------------------------- maxpool(3,2,1) 32 -> 16
__global__ __launch_bounds__(256) void pool32(const float* __restrict__ in,
                                              float* __restrict__ out)
{
    const int idx = blockIdx.x * 256 + threadIdx.x;   // 128*128*256
    const int p = idx & 255;
    const int nc = idx >> 8;
    const int oy = p >> 4, ox = p & 15;
    const float* ib = in + (size_t)nc * 1024;
    float m = 0.f;                                    // inputs >= 0
    #pragma unroll
    for (int dy = -1; dy <= 1; ++dy) {
        int iy = 2 * oy + dy;
        if ((unsigned)iy >= 32u) continue;
        #pragma unroll
        for (int dx = -1; dx <= 1; ++dx) {
            int ix = 2 * ox + dx;
            if ((unsigned)ix >= 32u) continue;
            m = fmaxf(m, ib[iy * 32 + ix]);
        }
    }
    out[(size_t)nc * 256 + p] = m;
}

// --------------------------- maxpool(3,2,0) 16->7 + global max == max over [0,15)^2
__global__ __launch_bounds__(256) void gmax_k(const float* __restrict__ in,
                                              float* __restrict__ g)
{
    const int idx = blockIdx.x * 256 + threadIdx.x;   // 16384 = n*128+c
    const float* ib = in + (size_t)idx * 256;
    float m = 0.f;                                    // inputs >= 0
    for (int y = 0; y < 15; ++y)
        #pragma unroll
        for (int x = 0; x < 15; ++x) m = fmaxf(m, ib[y * 16 + x]);
    g[idx] = m;
}

// ------------------------------------------------------------------- MLP
__global__ __launch_bounds__(256) void mlp_k(
    const float* __restrict__ g, const float* __restrict__ w,
    const float* __restrict__ b, float* __restrict__ out)
{
    const int idx = blockIdx.x * 256 + threadIdx.x;
    if (idx >= 1280) return;
    const int n = idx / 10, k = idx - n * 10;
    float acc = b[k];
    for (int c = 0; c < CCH; ++c) acc += g[n * CCH + c] * w[k * CCH + c];
    out[idx] = acc;
}

// ==================================================================== launch
extern "C" void kernel_launch(void* const* d_in, const int* in_sizes, int n_in,
                              void* d_out, int out_size, void* d_ws, size_t ws_size,
                              hipStream_t stream)
{
    const float* x   = (const float*)d_in[0];
    const float* w1  = (const float*)d_in[1];
    const float* b1  = (const float*)d_in[2];
    const float* bng = (const float*)d_in[3];
    const float* bnb = (const float*)d_in[4];
    const float* fw[4] = {(const float*)d_in[5],  (const float*)d_in[8],
                          (const float*)d_in[11], (const float*)d_in[14]};
    const float* fb[4] = {(const float*)d_in[6],  (const float*)d_in[9],
                          (const float*)d_in[12], (const float*)d_in[15]};
    const float* rw[4] = {(const float*)d_in[7],  (const float*)d_in[10],
                          (const float*)d_in[13], (const float*)d_in[16]};
    const float* mw = (const float*)d_in[17];
    const float* mb = (const float*)d_in[18];
    float* out = (float*)d_out;

    float* ws = (float*)d_ws;
    float* A     = ws;                      // 16.78M floats  [128,128,32,32]
    float* Bf    = ws + 16777216;           // f buffer
    float* Ct    = ws + 2 * 16777216;       // t buffer
    float* D     = ws + 3 * 16777216;       // [128,128,16,16]
    float* stats = D + 4194304;             // 256
    float* scsh  = stats + 256;             // 256
    float* gm    = scsh + 256;              // 16384

    zero_stats<<<1, 256, 0, stream>>>(stats);
    conv1_stats<<<16384, 256, 0, stream>>>(x, w1, b1, stats);
    bn_finalize<<<1, 128, 0, stream>>>(stats, bng, bnb, scsh);
    conv1_bn_pool<<<32768, 256, 0, stream>>>(x, w1, b1, scsh, A);

    for (int s = 0; s < 2; ++s) {           // RCLs at 32x32
        conv3<32, true><<<4096, 256, 0, stream>>>(A, fw[s], fb[s], Bf);
        lrn_k<1024, false><<<512, 256, 0, stream>>>(Bf, nullptr, A);
        for (int it = 0; it < 3; ++it) {
            conv3<32, false><<<4096, 256, 0, stream>>>(A, rw[s], nullptr, Ct);
            lrn_k<1024, true><<<512, 256, 0, stream>>>(Bf, Ct, A);
        }
    }
    pool32<<<16384, 256, 0, stream>>>(A, D);
    for (int s = 2; s < 4; ++s) {           // RCLs at 16x16
        conv3<16, true><<<1024, 256, 0, stream>>>(D, fw[s], fb[s], Bf);
        lrn_k<256, false><<<128, 256, 0, stream>>>(Bf, nullptr, D);
        for (int it = 0; it < 3; ++it) {
            conv3<16, false><<<1024, 256, 0, stream>>>(D, rw[s], nullptr, Ct);
            lrn_k<256, true><<<128, 256, 0, stream>>>(Bf, Ct, D);
        }
    }
    gmax_k<<<64, 256, 0, stream>>>(D, gm);
    mlp_k<<<5, 256, 0, stream>>>(gm, mw, mb, out);
}

// Round 2
// 2673.287 us; speedup vs baseline: 4.3762x; 4.3762x over previous
//
#include <hip/hip_runtime.h>

// RCNN forward. conv3x3 layers on MFMA f16 (implicit GEMM), activations in
// [n][y][x][c] f16 layout. conv1/BN path fp32 (unchanged from R0 baseline).

#define CCH 128
constexpr float KAPPA = 0.001f / 17.0f;

typedef __attribute__((ext_vector_type(8))) _Float16 half8;
typedef __attribute__((ext_vector_type(4))) float f32x4;

union U4 { uint4 v; ushort us[8]; _Float16 h[8]; };

// ---------------------------------------------------------------- zero stats
__global__ __launch_bounds__(256) void zero_stats(float* __restrict__ s) {
    s[threadIdx.x] = 0.f;
}

// ------------------------------------------------- conv1 (5x5, 3->128) stats
__global__ __launch_bounds__(256) void conv1_stats(
    const float* __restrict__ x, const float* __restrict__ w,
    const float* __restrict__ bias, float* __restrict__ stats)
{
    __shared__ float xs[3 * 68 * 72];
    __shared__ float red[512];
    const int lid = blockIdx.x;                 // 16384 = 128n * 128c
    const int xcd = lid & 7, slot = lid >> 3;
    const int c = slot & 127;
    const int n = xcd + 8 * (slot >> 7);
    const int tid = threadIdx.x;

    const float* xn = x + (size_t)n * 3 * 4096;
    for (int idx = tid; idx < 3 * 68 * 72; idx += 256) {
        int ci = idx / 4896;
        int rem = idx - ci * 4896;
        int py = rem / 72;
        int px = rem - py * 72;
        int gy = py - 2, gx = px - 2;
        float v = 0.f;
        if ((unsigned)gy < 64u && (unsigned)gx < 64u)
            v = xn[ci * 4096 + gy * 64 + gx];
        xs[idx] = v;
    }
    __syncthreads();

    const float* wc = w + c * 75;
    const float bc = bias[c];
    float s = 0.f, s2 = 0.f;
    for (int g = tid; g < 1024; g += 256) {
        int y = g >> 4, x0 = (g & 15) * 4;
        float acc[4] = {bc, bc, bc, bc};
        #pragma unroll
        for (int ci = 0; ci < 3; ++ci)
            #pragma unroll
            for (int ky = 0; ky < 5; ++ky) {
                const float4* p = (const float4*)&xs[ci * 4896 + (y + ky) * 72 + x0];
                float4 a = p[0], b4 = p[1];
                float vv[8] = {a.x, a.y, a.z, a.w, b4.x, b4.y, b4.z, b4.w};
                #pragma unroll
                for (int kx = 0; kx < 5; ++kx) {
                    float wv = wc[ci * 25 + ky * 5 + kx];
                    #pragma unroll
                    for (int j = 0; j < 4; ++j) acc[j] += vv[j + kx] * wv;
                }
            }
        s  += acc[0] + acc[1] + acc[2] + acc[3];
        s2 += acc[0]*acc[0] + acc[1]*acc[1] + acc[2]*acc[2] + acc[3]*acc[3];
    }
    red[tid] = s; red[256 + tid] = s2;
    __syncthreads();
    for (int o = 128; o > 0; o >>= 1) {
        if (tid < o) { red[tid] += red[tid + o]; red[256 + tid] += red[256 + tid + o]; }
        __syncthreads();
    }
    if (tid == 0) { atomicAdd(&stats[c], red[0]); atomicAdd(&stats[c + 128], red[256]); }
}

// --------------------------------------------------------------- bn finalize
__global__ __launch_bounds__(128) void bn_finalize(
    const float* __restrict__ stats, const float* __restrict__ g,
    const float* __restrict__ b, float* __restrict__ scsh)
{
    const int c = threadIdx.x;
    const float M = 128.f * 4096.f;
    float mean = stats[c] / M;
    float var = stats[c + 128] / M - mean * mean;
    float rstd = rsqrtf(var + 1e-5f);
    float sc = g[c] * rstd;
    scsh[c] = sc;
    scsh[c + 128] = b[c] - mean * sc;
}

// ----------------------------------- conv1 + BN + relu + maxpool(3,2,1) 64->32
// writes A32 in [n][y][x][c] f16 layout
__global__ __launch_bounds__(256) void conv1_bn_pool(
    const float* __restrict__ x, const float* __restrict__ w,
    const float* __restrict__ bias, const float* __restrict__ scsh,
    _Float16* __restrict__ outp)
{
    __shared__ float xs[3 * 37 * 72];
    __shared__ float hs[33 * 65];
    const int lid = blockIdx.x;                 // 32768 = 128n * 128c * 2
    const int xcd = lid & 7, slot = lid >> 3;
    const int half = slot & 1;
    const int c = (slot >> 1) & 127;
    const int n = xcd + 8 * (slot >> 8);
    const int oy0 = half * 16;
    const int ybase = 2 * oy0 - 1;
    const int gybase = ybase - 2;
    const int tid = threadIdx.x;

    const float* xn = x + (size_t)n * 3 * 4096;
    for (int idx = tid; idx < 3 * 37 * 72; idx += 256) {
        int ci = idx / (37 * 72);
        int rem = idx - ci * (37 * 72);
        int ly = rem / 72;
        int px = rem - ly * 72;
        int gy = gybase + ly, gx = px - 2;
        float v = 0.f;
        if ((unsigned)gy < 64u && (unsigned)gx < 64u)
            v = xn[ci * 4096 + gy * 64 + gx];
        xs[idx] = v;
    }
    __syncthreads();

    const float* wc = w + c * 75;
    const float bc = bias[c];
    const float sc = scsh[c], sh = scsh[c + 128];
    for (int g = tid; g < 33 * 16; g += 256) {
        int hy = g >> 4, x0 = (g & 15) * 4;
        int ygl = ybase + hy;
        if ((unsigned)ygl < 64u) {
            float acc[4] = {bc, bc, bc, bc};
            #pragma unroll
            for (int ci = 0; ci < 3; ++ci)
                #pragma unroll
                for (int ky = 0; ky < 5; ++ky) {
                    const float4* p = (const float4*)&xs[ci * (37*72) + (hy + ky) * 72 + x0];
                    float4 a = p[0], b4 = p[1];
                    float vv[8] = {a.x, a.y, a.z, a.w, b4.x, b4.y, b4.z, b4.w};
                    #pragma unroll
                    for (int kx = 0; kx < 5; ++kx) {
                        float wv = wc[ci * 25 + ky * 5 + kx];
                        #pragma unroll
                        for (int j = 0; j < 4; ++j) acc[j] += vv[j + kx] * wv;
                    }
                }
            #pragma unroll
            for (int j = 0; j < 4; ++j)
                hs[hy * 65 + x0 + j] = fmaxf(acc[j] * sc + sh, 0.f);
        }
    }
    __syncthreads();

    _Float16* ob = outp + (size_t)n * 1024 * 128;
    for (int p = tid; p < 512; p += 256) {
        int oyl = p >> 5, ox = p & 31;
        int oy = oy0 + oyl;
        float m = 0.f;
        #pragma unroll
        for (int dy = -1; dy <= 1; ++dy) {
            int iy = 2 * oy + dy;
            if ((unsigned)iy >= 64u) continue;
            int hr = iy - ybase;
            #pragma unroll
            for (int dx = -1; dx <= 1; ++dx) {
                int ix = 2 * ox + dx;
                if ((unsigned)ix >= 64u) continue;
                m = fmaxf(m, hs[hr * 65 + ix]);
            }
        }
        ob[(oy * 32 + ox) * 128 + c] = (_Float16)m;
    }
}

// --------------------------------------- weight convert fp32 [co][ci][3][3]
//                                      -> f16 [tap][co][ci]
__global__ __launch_bounds__(256) void wcvt(const float* __restrict__ wsrc,
                                            _Float16* __restrict__ wdst)
{
    const int idx = blockIdx.x * 256 + threadIdx.x;   // 147456
    const int t = idx >> 14;
    const int rem = idx & 16383;
    const int co = rem >> 7;
    const int ci = rem & 127;
    wdst[idx] = (_Float16)wsrc[(co * 128 + ci) * 9 + t];
}

// --------------------------------------------- conv3x3 MFMA (128->128, pad 1)
// block = 1 image x 8-row strip, 4 waves; wave = 128 co x (2 rows of W) px.
// LDS: X chunk [10 rows][W+2][32ci] f16, 80B/pixel pitch; epilogue bounce f32.
template<int H, bool ADD_F>
__global__ __launch_bounds__(256, 2) void conv3(
    const _Float16* __restrict__ in, const _Float16* __restrict__ wb,
    const float* __restrict__ bias, const _Float16* __restrict__ fadd,
    _Float16* __restrict__ outp)
{
    constexpr int W = H, HW = H * W;
    constexpr int XP = W + 2;
    constexpr int PITCH = 40;                  // f16 per pixel slot (32 used)
    constexpr int ROWS = 10;
    constexpr int PTN = (H == 32) ? 4 : 2;
    constexpr int NPIX = PTN * 16;
    constexpr int STAGE = ROWS * XP * PITCH;   // f16 count
    constexpr int TASKS = ROWS * W * 4;
    constexpr int NIT = (TASKS + 255) / 256;
    constexpr int LOG4W = (H == 32) ? 7 : 6;
    constexpr int LDSF = 4 * NPIX * 36;        // floats; also >= STAGE/2

    __shared__ float ldsf[LDSF];
    _Float16* xs = (_Float16*)ldsf;

    const int bid = blockIdx.x;
    const int slot = bid >> 3;
    const int n = (bid & 7) + 8 * (slot & 15);
    const int y0 = (slot >> 4) * 8;
    const int tid = threadIdx.x;
    const int w = tid >> 6, l = tid & 63;
    const int l15 = l & 15, lg = l >> 4;

    for (int i = tid; i < STAGE / 2; i += 256) ((uint*)xs)[i] = 0;

    f32x4 acc[8][PTN];
    #pragma unroll
    for (int cot = 0; cot < 8; ++cot) {
        f32x4 bv = {0.f, 0.f, 0.f, 0.f};
        if constexpr (!ADD_F) bv = *(const f32x4*)&bias[cot * 16 + lg * 4];
        #pragma unroll
        for (int pt = 0; pt < PTN; ++pt) acc[cot][pt] = bv;
    }

    const _Float16* inb = in + (size_t)n * HW * 128;
    uint4 stg[NIT];

    auto issue = [&](int c0) {
        #pragma unroll
        for (int i = 0; i < NIT; ++i) {
            int t = tid + i * 256;
            uint4 v = {0u, 0u, 0u, 0u};
            if (TASKS % 256 == 0 || t < TASKS) {
                int g = t & 3, xx = (t >> 2) & (W - 1), yl = t >> LOG4W;
                int gy = y0 - 1 + yl;
                if ((unsigned)gy < (unsigned)H)
                    v = *(const uint4*)&inb[((size_t)(gy * W + xx)) * 128 + c0 + g * 8];
            }
            stg[i] = v;
        }
    };
    auto commit = [&]() {
        #pragma unroll
        for (int i = 0; i < NIT; ++i) {
            int t = tid + i * 256;
            if (TASKS % 256 == 0 || t < TASKS) {
                int g = t & 3, xx = (t >> 2) & (W - 1), yl = t >> LOG4W;
                *(uint4*)&xs[(yl * XP + xx + 1) * PITCH + g * 8] = stg[i];
            }
        }
    };

    int bofs[PTN];
    #pragma unroll
    for (int pt = 0; pt < PTN; ++pt) {
        int row_l = 2 * w + ((H == 32) ? (pt >> 1) : pt);
        int xb = ((H == 32) ? (pt & 1) * 16 : 0) + l15;
        bofs[pt] = ((row_l + 1) * XP + xb + 1) * PITCH + lg * 8;
    }
    const _Float16* wl = wb + l15 * 128 + lg * 8;

    issue(0);
    for (int cc = 0; cc < 4; ++cc) {
        const int c0 = cc * 32;
        __syncthreads();
        commit();
        if (cc < 3) issue(c0 + 32);
        __syncthreads();
        #pragma unroll
        for (int ky = -1; ky <= 1; ++ky)
            #pragma unroll
            for (int kx = -1; kx <= 1; ++kx) {
                const int t9 = (ky + 1) * 3 + (kx + 1);
                half8 bf[PTN];
                #pragma unroll
                for (int pt = 0; pt < PTN; ++pt)
                    bf[pt] = *(const half8*)&xs[bofs[pt] + (ky * XP + kx) * PITCH];
                const _Float16* wt = wl + t9 * 16384 + c0;
                #pragma unroll
                for (int coh = 0; coh < 2; ++coh) {
                    half8 av[4];
                    #pragma unroll
                    for (int j = 0; j < 4; ++j)
                        av[j] = *(const half8*)&wt[(coh * 4 + j) * 2048];
                    #pragma unroll
                    for (int j = 0; j < 4; ++j)
                        #pragma unroll
                        for (int pt = 0; pt < PTN; ++pt)
                            acc[coh * 4 + j][pt] = __builtin_amdgcn_mfma_f32_16x16x32_f16(
                                av[j], bf[pt], acc[coh * 4 + j][pt], 0, 0, 0);
                }
            }
    }

    // -------- epilogue: per-wave LDS bounce -> [pix][co] f16 stores (+f add)
    __syncthreads();
    float* bw = ldsf + w * (NPIX * 36);
    const int pix = (H == 32) ? l : (l & 31);
    const int sub = (H == 32) ? 0 : (l >> 5);
    constexpr int NCO = (H == 32) ? 32 : 16;
    const int row_l = 2 * w + ((H == 32) ? (pix >> 5) : (pix >> 4));
    const int xo = pix & (W - 1);
    const size_t gbase = ((size_t)n * HW + (size_t)(y0 + row_l) * W + xo) * 128;

    #pragma unroll
    for (int q = 0; q < 4; ++q) {
        #pragma unroll
        for (int j = 0; j < 2; ++j)
            #pragma unroll
            for (int pt = 0; pt < PTN; ++pt) {
                int p = pt * 16 + l15;
                *(f32x4*)&bw[p * 36 + j * 16 + lg * 4] = acc[2 * q + j][pt];
            }
        const int cofs = q * 32 + sub * 16;
        #pragma unroll
        for (int j8 = 0; j8 < NCO / 8; ++j8) {
            f32x4 v0 = *(const f32x4*)&bw[pix * 36 + sub * 16 + j8 * 8];
            f32x4 v1 = *(const f32x4*)&bw[pix * 36 + sub * 16 + j8 * 8 + 4];
            float vv[8];
            #pragma unroll
            for (int i = 0; i < 4; ++i) { vv[i] = v0[i]; vv[4 + i] = v1[i]; }
            if constexpr (ADD_F) {
                U4 fv; fv.v = *(const uint4*)&fadd[gbase + cofs + j8 * 8];
                #pragma unroll
                for (int i = 0; i < 8; ++i) vv[i] += (float)fv.h[i];
            }
            U4 o;
            #pragma unroll
            for (int i = 0; i < 8; ++i) o.h[i] = (_Float16)vv[i];
            *(uint4*)&outp[gbase + cofs + j8 * 8] = o.v;
        }
    }
}

// ------------------------------------------------------------------- LRN
// [n][pix][c] layout: per-thread contiguous 256B in/out. z = relu(s);
// out = z * (win17 sum z^2 * k + 1)^-0.75
__global__ __launch_bounds__(256) void lrn_k(const _Float16* __restrict__ s,
                                             _Float16* __restrict__ r)
{
    const int idx = blockIdx.x * 256 + threadIdx.x;
    const _Float16* sb = s + (size_t)idx * 128;
    _Float16* rb = r + (size_t)idx * 128;
    U4 sv[16];
    #pragma unroll
    for (int i = 0; i < 16; ++i) sv[i].v = ((const uint4*)sb)[i];
    float ring[17], zr[9], wsum = 0.f;
    #pragma unroll
    for (int i = 0; i < 17; ++i) ring[i] = 0.f;
    #pragma unroll
    for (int i = 0; i < 9; ++i) zr[i] = 0.f;
    U4 ob;
    #pragma unroll
    for (int c = 0; c < 136; ++c) {
        float z = 0.f;
        if (c < 128) {
            float v = (float)sv[c >> 3].h[c & 7];
            z = v > 0.f ? v : 0.f;
        }
        float zz = z * z;
        wsum += zz - ring[c % 17];
        ring[c % 17] = zz;
        zr[c % 9] = z;
        if (c >= 8) {
            int o = c - 8;
            float p75 = exp2f(-0.75f * log2f(wsum * KAPPA + 1.f));
            ob.h[o & 7] = (_Float16)(zr[(c + 1) % 9] * p75);
            if ((o & 7) == 7) ((uint4*)rb)[o >> 3] = ob.v;
        }
    }
}

// -------------------------------------------------- maxpool(3,2,1) 32 -> 16
__global__ __launch_bounds__(256) void pool32(const _Float16* __restrict__ in,
                                              _Float16* __restrict__ out)
{
    const int idx = blockIdx.x * 256 + threadIdx.x;   // (n*256+opix)*128+c
    const int c = idx & 127;
    const int rest = idx >> 7;
    const int opix = rest & 255;
    const int n = rest >> 8;
    const int oy = opix >> 4, ox = opix & 15;
    const _Float16* ib = in + (size_t)n * 1024 * 128;
    float m = 0.f;
    #pragma unroll
    for (int dy = -1; dy <= 1; ++dy) {
        int iy = 2 * oy + dy;
        if ((unsigned)iy >= 32u) continue;
        #pragma unroll
        for (int dx = -1; dx <= 1; ++dx) {
            int ix = 2 * ox + dx;
            if ((unsigned)ix >= 32u) continue;
            m = fmaxf(m, (float)ib[(iy * 32 + ix) * 128 + c]);
        }
    }
    out[idx] = (_Float16)m;
}

// --------------------------- maxpool(3,2,0)+global max == max over [0,15)^2
__global__ __launch_bounds__(256) void gmax_k(const _Float16* __restrict__ in,
                                              float* __restrict__ g)
{
    const int idx = blockIdx.x * 256 + threadIdx.x;   // n*128+c
    const int c = idx & 127;
    const int n = idx >> 7;
    const _Float16* ib = in + (size_t)n * 256 * 128;
    float m = 0.f;
    for (int y = 0; y < 15; ++y)
        #pragma unroll
        for (int x = 0; x < 15; ++x)
            m = fmaxf(m, (float)ib[(y * 16 + x) * 128 + c]);
    g[idx] = m;
}

// ------------------------------------------------------------------- MLP
__global__ __launch_bounds__(256) void mlp_k(
    const float* __restrict__ g, const float* __restrict__ w,
    const float* __restrict__ b, float* __restrict__ out)
{
    const int idx = blockIdx.x * 256 + threadIdx.x;
    if (idx >= 1280) return;
    const int n = idx / 10, k = idx - n * 10;
    float acc = b[k];
    for (int c = 0; c < CCH; ++c) acc += g[n * CCH + c] * w[k * CCH + c];
    out[idx] = acc;
}

// ==================================================================== launch
extern "C" void kernel_launch(void* const* d_in, const int* in_sizes, int n_in,
                              void* d_out, int out_size, void* d_ws, size_t ws_size,
                              hipStream_t stream)
{
    const float* x   = (const float*)d_in[0];
    const float* w1  = (const float*)d_in[1];
    const float* b1  = (const float*)d_in[2];
    const float* bng = (const float*)d_in[3];
    const float* bnb = (const float*)d_in[4];
    const float* fw[4] = {(const float*)d_in[5],  (const float*)d_in[8],
                          (const float*)d_in[11], (const float*)d_in[14]};
    const float* fb[4] = {(const float*)d_in[6],  (const float*)d_in[9],
                          (const float*)d_in[12], (const float*)d_in[15]};
    const float* rw[4] = {(const float*)d_in[7],  (const float*)d_in[10],
                          (const float*)d_in[13], (const float*)d_in[16]};
    const float* mw = (const float*)d_in[17];
    const float* mb = (const float*)d_in[18];
    float* out = (float*)d_out;

    _Float16* ws16 = (_Float16*)d_ws;
    _Float16* A32  = ws16;                       // [128][32][32][128]
    _Float16* F32  = ws16 + 16777216;
    _Float16* S32  = ws16 + 2 * 16777216;
    _Float16* A16  = ws16 + 3 * 16777216;        // [128][16][16][128]
    _Float16* F16b = A16 + 4194304;
    _Float16* S16b = A16 + 2 * 4194304;
    _Float16* Wb   = A16 + 3 * 4194304;          // 8 layers x [9][128][128]
    float* stats = (float*)(Wb + 8 * 147456);
    float* scsh  = stats + 256;
    float* gm    = scsh + 256;

    zero_stats<<<1, 256, 0, stream>>>(stats);
    conv1_stats<<<16384, 256, 0, stream>>>(x, w1, b1, stats);
    bn_finalize<<<1, 128, 0, stream>>>(stats, bng, bnb, scsh);
    conv1_bn_pool<<<32768, 256, 0, stream>>>(x, w1, b1, scsh, A32);

    const float* lw[8] = {fw[0], rw[0], fw[1], rw[1], fw[2], rw[2], fw[3], rw[3]};
    for (int i = 0; i < 8; ++i)
        wcvt<<<576, 256, 0, stream>>>(lw[i], Wb + i * 147456);

    for (int s = 0; s < 2; ++s) {
        conv3<32, false><<<512, 256, 0, stream>>>(A32, Wb + (2*s) * 147456, fb[s], nullptr, F32);
        lrn_k<<<512, 256, 0, stream>>>(F32, A32);
        for (int it = 0; it < 3; ++it) {
            conv3<32, true><<<512, 256, 0, stream>>>(A32, Wb + (2*s+1) * 147456, nullptr, F32, S32);
            lrn_k<<<512, 256, 0, stream>>>(S32, A32);
        }
    }
    pool32<<<16384, 256, 0, stream>>>(A32, A16);
    for (int s = 2; s < 4; ++s) {
        conv3<16, false><<<256, 256, 0, stream>>>(A16, Wb + (2*s) * 147456, fb[s], nullptr, F16b);
        lrn_k<<<128, 256, 0, stream>>>(F16b, A16);
        for (int it = 0; it < 3; ++it) {
            conv3<16, true><<<256, 256, 0, stream>>>(A16, Wb + (2*s+1) * 147456, nullptr, F16b, S16b);
            lrn_k<<<128, 256, 0, stream>>>(S16b, A16);
        }
    }
    gmax_k<<<64, 256, 0, stream>>>(A16, gm);
    mlp_k<<<5, 256, 0, stream>>>(gm, mw, mb, out);
}

// Round 3
// 2233.153 us; speedup vs baseline: 5.2387x; 1.1971x over previous
//
#include <hip/hip_runtime.h>

// RCNN forward. conv3x3 layers on MFMA f16 (implicit GEMM), activations in
// [n][y][x][c] f16 layout. conv1 path: x-in-registers stats pass + x-in-LDS
// compute+BN+pool pass (all 128 co per x staging).

#define CCH 128
constexpr float KAPPA = 0.001f / 17.0f;

typedef __attribute__((ext_vector_type(8))) _Float16 half8;
typedef __attribute__((ext_vector_type(4))) float f32x4;

union U4 { uint4 v; ushort us[8]; _Float16 h[8]; };

// ---------------------------------------------------------------- zero stats
__global__ __launch_bounds__(256) void zero_stats(float* __restrict__ s) {
    s[threadIdx.x] = 0.f;
}

// ---------------------------------------- conv1 stats: x in regs, co loop
// grid 512 = 128 n x 4 strips of 16 rows; thread = (yl, xg) 4 px.
__global__ __launch_bounds__(256, 2) void conv1_stats2(
    const float* __restrict__ x, const float* __restrict__ w,
    const float* __restrict__ bias, float* __restrict__ stats)
{
    __shared__ float ps[4][128], ps2[4][128];
    const int bid = blockIdx.x;
    const int n = bid & 127;
    const int y0 = (bid >> 7) * 16;
    const int tid = threadIdx.x;
    const int yl = tid >> 4, xg = tid & 15;
    const int y = y0 + yl, x0 = xg * 4;
    const int wv = tid >> 6, lane = tid & 63;

    const float* xn = x + (size_t)n * 3 * 4096;
    float xr[3][5][8];
    #pragma unroll
    for (int ci = 0; ci < 3; ++ci)
        #pragma unroll
        for (int ky = 0; ky < 5; ++ky) {
            int gy = y + ky - 2;
            const float* row = xn + ci * 4096 + gy * 64;
            bool yok = (unsigned)gy < 64u;
            #pragma unroll
            for (int j = 0; j < 8; ++j) {
                int gx = x0 - 2 + j;
                xr[ci][ky][j] = (yok && (unsigned)gx < 64u) ? row[gx] : 0.f;
            }
        }

    for (int co = 0; co < 128; ++co) {
        const float* wc = w + co * 75;
        const float bc = bias[co];
        float a[4] = {bc, bc, bc, bc};
        #pragma unroll
        for (int ci = 0; ci < 3; ++ci)
            #pragma unroll
            for (int ky = 0; ky < 5; ++ky)
                #pragma unroll
                for (int kx = 0; kx < 5; ++kx) {
                    float wvv = wc[ci * 25 + ky * 5 + kx];
                    #pragma unroll
                    for (int j = 0; j < 4; ++j) a[j] += xr[ci][ky][j + kx] * wvv;
                }
        float s = a[0] + a[1] + a[2] + a[3];
        float s2 = a[0]*a[0] + a[1]*a[1] + a[2]*a[2] + a[3]*a[3];
        #pragma unroll
        for (int o = 1; o < 64; o <<= 1) {
            s  += __shfl_xor(s, o, 64);
            s2 += __shfl_xor(s2, o, 64);
        }
        if (lane == 0) { ps[wv][co] = s; ps2[wv][co] = s2; }
    }
    __syncthreads();
    if (tid < 128) {
        float A = ps[0][tid] + ps[1][tid] + ps[2][tid] + ps[3][tid];
        float B = ps2[0][tid] + ps2[1][tid] + ps2[2][tid] + ps2[3][tid];
        atomicAdd(&stats[tid], A);
        atomicAdd(&stats[tid + 128], B);
    }
}

// --------------------------------------------------------------- bn finalize
__global__ __launch_bounds__(128) void bn_finalize(
    const float* __restrict__ stats, const float* __restrict__ g,
    const float* __restrict__ b, float* __restrict__ scsh)
{
    const int c = threadIdx.x;
    const float M = 128.f * 4096.f;
    float mean = stats[c] / M;
    float var = stats[c + 128] / M - mean * mean;
    float rstd = rsqrtf(var + 1e-5f);
    float sc = g[c] * rstd;
    scsh[c] = sc;
    scsh[c + 128] = b[c] - mean * sc;
}

// ------------------- conv1 + BN + relu + maxpool(3,2,1): x in LDS, co loop
// grid 256 = 128 n x 2 co-halves. Per co: compute h plane -> LDS -> pool.
__global__ __launch_bounds__(256, 2) void conv1_pool(
    const float* __restrict__ x, const float* __restrict__ w,
    const float* __restrict__ bias, const float* __restrict__ scsh,
    _Float16* __restrict__ out)
{
    __shared__ float xs[3 * 68 * 72];     // 57.4 KB
    __shared__ float hb[64 * 66];         // 16.5 KB
    const int bid = blockIdx.x;
    const int n = bid & 127;
    const int half = bid >> 7;
    const int tid = threadIdx.x;

    const float* xn = x + (size_t)n * 3 * 4096;
    for (int idx = tid; idx < 3 * 68 * 72; idx += 256) {
        int ci = idx / 4896;
        int rem = idx - ci * 4896;
        int py = rem / 72;
        int px = rem - py * 72;
        int gy = py - 2, gx = px - 2;
        float v = 0.f;
        if ((unsigned)gy < 64u && (unsigned)gx < 64u)
            v = xn[ci * 4096 + gy * 64 + gx];
        xs[idx] = v;
    }

    U4 opk[4];
    _Float16* ob = out + (size_t)n * 1024 * 128 + half * 64;

    for (int col = 0; col < 64; ++col) {
        const int co = half * 64 + col;
        const float* wc = w + co * 75;
        const float bc = bias[co];
        const float sc = scsh[co], sh = scsh[co + 128];
        __syncthreads();                  // hb consumed by previous iter
        for (int i = 0; i < 4; ++i) {
            int g = tid + i * 256;        // 1024 groups of 4 px
            int y = g >> 4, x0 = (g & 15) * 4;
            float a[4] = {bc, bc, bc, bc};
            #pragma unroll
            for (int ci = 0; ci < 3; ++ci)
                #pragma unroll
                for (int ky = 0; ky < 5; ++ky) {
                    const float4* p = (const float4*)&xs[ci * 4896 + (y + ky) * 72 + x0];
                    float4 v0 = p[0], v1 = p[1];
                    float vv[8] = {v0.x, v0.y, v0.z, v0.w, v1.x, v1.y, v1.z, v1.w};
                    #pragma unroll
                    for (int kx = 0; kx < 5; ++kx) {
                        float wvv = wc[ci * 25 + ky * 5 + kx];
                        #pragma unroll
                        for (int j = 0; j < 4; ++j) a[j] += vv[j + kx] * wvv;
                    }
                }
            #pragma unroll
            for (int j = 0; j < 4; ++j)
                hb[y * 66 + x0 + j] = fmaxf(a[j] * sc + sh, 0.f);
        }
        __syncthreads();
        const int q = col & 7;
        #pragma unroll
        for (int i = 0; i < 4; ++i) {
            int o = tid + i * 256;        // 1024 pooled outputs
            int oy = o >> 5, ox = o & 31;
            float m = 0.f;
            #pragma unroll
            for (int dy = -1; dy <= 1; ++dy) {
                int iy = 2 * oy + dy;
                if ((unsigned)iy >= 64u) continue;
                #pragma unroll
                for (int dx = -1; dx <= 1; ++dx) {
                    int ix = 2 * ox + dx;
                    if ((unsigned)ix >= 64u) continue;
                    m = fmaxf(m, hb[iy * 66 + ix]);
                }
            }
            opk[i].h[q] = (_Float16)m;
        }
        if (q == 7) {
            const int cobase = col - 7;
            #pragma unroll
            for (int i = 0; i < 4; ++i) {
                int o = tid + i * 256;
                *(uint4*)&ob[(size_t)o * 128 + cobase] = opk[i].v;
            }
        }
    }
}

// --------------------------------------- weight convert fp32 [co][ci][3][3]
//                                      -> f16 [tap][co][ci]
__global__ __launch_bounds__(256) void wcvt(const float* __restrict__ wsrc,
                                            _Float16* __restrict__ wdst)
{
    const int idx = blockIdx.x * 256 + threadIdx.x;   // 147456
    const int t = idx >> 14;
    const int rem = idx & 16383;
    const int co = rem >> 7;
    const int ci = rem & 127;
    wdst[idx] = (_Float16)wsrc[(co * 128 + ci) * 9 + t];
}

// --------------------------------------------- conv3x3 MFMA (128->128, pad 1)
// block = 1 image x 8-row strip, 4 waves; wave = 128 co x (2 rows of W) px.
// LDS: X chunk [10 rows][W+2][32ci] f16, 80B/pixel pitch; epilogue bounce f32.
template<int H, bool ADD_F>
__global__ __launch_bounds__(256, 2) void conv3(
    const _Float16* __restrict__ in, const _Float16* __restrict__ wb,
    const float* __restrict__ bias, const _Float16* __restrict__ fadd,
    _Float16* __restrict__ outp)
{
    constexpr int W = H, HW = H * W;
    constexpr int XP = W + 2;
    constexpr int PITCH = 40;                  // f16 per pixel slot (32 used)
    constexpr int ROWS = 10;
    constexpr int PTN = (H == 32) ? 4 : 2;
    constexpr int NPIX = PTN * 16;
    constexpr int STAGE = ROWS * XP * PITCH;   // f16 count
    constexpr int TASKS = ROWS * W * 4;
    constexpr int NIT = (TASKS + 255) / 256;
    constexpr int LOG4W = (H == 32) ? 7 : 6;
    constexpr int LDSF = 4 * NPIX * 36;        // floats; also >= STAGE/2

    __shared__ float ldsf[LDSF];
    _Float16* xs = (_Float16*)ldsf;

    const int bid = blockIdx.x;
    const int slot = bid >> 3;
    const int n = (bid & 7) + 8 * (slot & 15);
    const int y0 = (slot >> 4) * 8;
    const int tid = threadIdx.x;
    const int w = tid >> 6, l = tid & 63;
    const int l15 = l & 15, lg = l >> 4;

    for (int i = tid; i < STAGE / 2; i += 256) ((uint*)xs)[i] = 0;

    f32x4 acc[8][PTN];
    #pragma unroll
    for (int cot = 0; cot < 8; ++cot) {
        f32x4 bv = {0.f, 0.f, 0.f, 0.f};
        if constexpr (!ADD_F) bv = *(const f32x4*)&bias[cot * 16 + lg * 4];
        #pragma unroll
        for (int pt = 0; pt < PTN; ++pt) acc[cot][pt] = bv;
    }

    const _Float16* inb = in + (size_t)n * HW * 128;
    uint4 stg[NIT];

    auto issue = [&](int c0) {
        #pragma unroll
        for (int i = 0; i < NIT; ++i) {
            int t = tid + i * 256;
            uint4 v = {0u, 0u, 0u, 0u};
            if (TASKS % 256 == 0 || t < TASKS) {
                int g = t & 3, xx = (t >> 2) & (W - 1), yl = t >> LOG4W;
                int gy = y0 - 1 + yl;
                if ((unsigned)gy < (unsigned)H)
                    v = *(const uint4*)&inb[((size_t)(gy * W + xx)) * 128 + c0 + g * 8];
            }
            stg[i] = v;
        }
    };
    auto commit = [&]() {
        #pragma unroll
        for (int i = 0; i < NIT; ++i) {
            int t = tid + i * 256;
            if (TASKS % 256 == 0 || t < TASKS) {
                int g = t & 3, xx = (t >> 2) & (W - 1), yl = t >> LOG4W;
                *(uint4*)&xs[(yl * XP + xx + 1) * PITCH + g * 8] = stg[i];
            }
        }
    };

    int bofs[PTN];
    #pragma unroll
    for (int pt = 0; pt < PTN; ++pt) {
        int row_l = 2 * w + ((H == 32) ? (pt >> 1) : pt);
        int xb = ((H == 32) ? (pt & 1) * 16 : 0) + l15;
        bofs[pt] = ((row_l + 1) * XP + xb + 1) * PITCH + lg * 8;
    }
    const _Float16* wl = wb + l15 * 128 + lg * 8;

    issue(0);
    for (int cc = 0; cc < 4; ++cc) {
        const int c0 = cc * 32;
        __syncthreads();
        commit();
        if (cc < 3) issue(c0 + 32);
        __syncthreads();
        #pragma unroll
        for (int ky = -1; ky <= 1; ++ky)
            #pragma unroll
            for (int kx = -1; kx <= 1; ++kx) {
                const int t9 = (ky + 1) * 3 + (kx + 1);
                half8 bf[PTN];
                #pragma unroll
                for (int pt = 0; pt < PTN; ++pt)
                    bf[pt] = *(const half8*)&xs[bofs[pt] + (ky * XP + kx) * PITCH];
                const _Float16* wt = wl + t9 * 16384 + c0;
                #pragma unroll
                for (int coh = 0; coh < 2; ++coh) {
                    half8 av[4];
                    #pragma unroll
                    for (int j = 0; j < 4; ++j)
                        av[j] = *(const half8*)&wt[(coh * 4 + j) * 2048];
                    #pragma unroll
                    for (int j = 0; j < 4; ++j)
                        #pragma unroll
                        for (int pt = 0; pt < PTN; ++pt)
                            acc[coh * 4 + j][pt] = __builtin_amdgcn_mfma_f32_16x16x32_f16(
                                av[j], bf[pt], acc[coh * 4 + j][pt], 0, 0, 0);
                }
            }
    }

    // -------- epilogue: per-wave LDS bounce -> [pix][co] f16 stores (+f add)
    __syncthreads();
    float* bw = ldsf + w * (NPIX * 36);
    const int pix = (H == 32) ? l : (l & 31);
    const int sub = (H == 32) ? 0 : (l >> 5);
    constexpr int NCO = (H == 32) ? 32 : 16;
    const int row_l = 2 * w + ((H == 32) ? (pix >> 5) : (pix >> 4));
    const int xo = pix & (W - 1);
    const size_t gbase = ((size_t)n * HW + (size_t)(y0 + row_l) * W + xo) * 128;

    #pragma unroll
    for (int q = 0; q < 4; ++q) {
        #pragma unroll
        for (int j = 0; j < 2; ++j)
            #pragma unroll
            for (int pt = 0; pt < PTN; ++pt) {
                int p = pt * 16 + l15;
                *(f32x4*)&bw[p * 36 + j * 16 + lg * 4] = acc[2 * q + j][pt];
            }
        const int cofs = q * 32 + sub * 16;
        #pragma unroll
        for (int j8 = 0; j8 < NCO / 8; ++j8) {
            f32x4 v0 = *(const f32x4*)&bw[pix * 36 + sub * 16 + j8 * 8];
            f32x4 v1 = *(const f32x4*)&bw[pix * 36 + sub * 16 + j8 * 8 + 4];
            float vv[8];
            #pragma unroll
            for (int i = 0; i < 4; ++i) { vv[i] = v0[i]; vv[4 + i] = v1[i]; }
            if constexpr (ADD_F) {
                U4 fv; fv.v = *(const uint4*)&fadd[gbase + cofs + j8 * 8];
                #pragma unroll
                for (int i = 0; i < 8; ++i) vv[i] += (float)fv.h[i];
            }
            U4 o;
            #pragma unroll
            for (int i = 0; i < 8; ++i) o.h[i] = (_Float16)vv[i];
            *(uint4*)&outp[gbase + cofs + j8 * 8] = o.v;
        }
    }
}

// ------------------------------------------------------------------- LRN
__global__ __launch_bounds__(256) void lrn_k(const _Float16* __restrict__ s,
                                             _Float16* __restrict__ r)
{
    const int idx = blockIdx.x * 256 + threadIdx.x;
    const _Float16* sb = s + (size_t)idx * 128;
    _Float16* rb = r + (size_t)idx * 128;
    U4 sv[16];
    #pragma unroll
    for (int i = 0; i < 16; ++i) sv[i].v = ((const uint4*)sb)[i];
    float ring[17], zr[9], wsum = 0.f;
    #pragma unroll
    for (int i = 0; i < 17; ++i) ring[i] = 0.f;
    #pragma unroll
    for (int i = 0; i < 9; ++i) zr[i] = 0.f;
    U4 ob;
    #pragma unroll
    for (int c = 0; c < 136; ++c) {
        float z = 0.f;
        if (c < 128) {
            float v = (float)sv[c >> 3].h[c & 7];
            z = v > 0.f ? v : 0.f;
        }
        float zz = z * z;
        wsum += zz - ring[c % 17];
        ring[c % 17] = zz;
        zr[c % 9] = z;
        if (c >= 8) {
            int o = c - 8;
            float p75 = exp2f(-0.75f * log2f(wsum * KAPPA + 1.f));
            ob.h[o & 7] = (_Float16)(zr[(c + 1) % 9] * p75);
            if ((o & 7) == 7) ((uint4*)rb)[o >> 3] = ob.v;
        }
    }
}

// -------------------------------------------------- maxpool(3,2,1) 32 -> 16
__global__ __launch_bounds__(256) void pool32(const _Float16* __restrict__ in,
                                              _Float16* __restrict__ out)
{
    const int idx = blockIdx.x * 256 + threadIdx.x;
    const int c = idx & 127;
    const int rest = idx >> 7;
    const int opix = rest & 255;
    const int n = rest >> 8;
    const int oy = opix >> 4, ox = opix & 15;
    const _Float16* ib = in + (size_t)n * 1024 * 128;
    float m = 0.f;
    #pragma unroll
    for (int dy = -1; dy <= 1; ++dy) {
        int iy = 2 * oy + dy;
        if ((unsigned)iy >= 32u) continue;
        #pragma unroll
        for (int dx = -1; dx <= 1; ++dx) {
            int ix = 2 * ox + dx;
            if ((unsigned)ix >= 32u) continue;
            m = fmaxf(m, (float)ib[(iy * 32 + ix) * 128 + c]);
        }
    }
    out[idx] = (_Float16)m;
}

// --------------------------- maxpool(3,2,0)+global max == max over [0,15)^2
__global__ __launch_bounds__(256) void gmax_k(const _Float16* __restrict__ in,
                                              float* __restrict__ g)
{
    const int idx = blockIdx.x * 256 + threadIdx.x;
    const int c = idx & 127;
    const int n = idx >> 7;
    const _Float16* ib = in + (size_t)n * 256 * 128;
    float m = 0.f;
    for (int y = 0; y < 15; ++y)
        #pragma unroll
        for (int x = 0; x < 15; ++x)
            m = fmaxf(m, (float)ib[(y * 16 + x) * 128 + c]);
    g[idx] = m;
}

// ------------------------------------------------------------------- MLP
__global__ __launch_bounds__(256) void mlp_k(
    const float* __restrict__ g, const float* __restrict__ w,
    const float* __restrict__ b, float* __restrict__ out)
{
    const int idx = blockIdx.x * 256 + threadIdx.x;
    if (idx >= 1280) return;
    const int n = idx / 10, k = idx - n * 10;
    float acc = b[k];
    for (int c = 0; c < CCH; ++c) acc += g[n * CCH + c] * w[k * CCH + c];
    out[idx] = acc;
}

// ==================================================================== launch
extern "C" void kernel_launch(void* const* d_in, const int* in_sizes, int n_in,
                              void* d_out, int out_size, void* d_ws, size_t ws_size,
                              hipStream_t stream)
{
    const float* x   = (const float*)d_in[0];
    const float* w1  = (const float*)d_in[1];
    const float* b1  = (const float*)d_in[2];
    const float* bng = (const float*)d_in[3];
    const float* bnb = (const float*)d_in[4];
    const float* fw[4] = {(const float*)d_in[5],  (const float*)d_in[8],
                          (const float*)d_in[11], (const float*)d_in[14]};
    const float* fb[4] = {(const float*)d_in[6],  (const float*)d_in[9],
                          (const float*)d_in[12], (const float*)d_in[15]};
    const float* rw[4] = {(const float*)d_in[7],  (const float*)d_in[10],
                          (const float*)d_in[13], (const float*)d_in[16]};
    const float* mw = (const float*)d_in[17];
    const float* mb = (const float*)d_in[18];
    float* out = (float*)d_out;

    _Float16* ws16 = (_Float16*)d_ws;
    _Float16* A32  = ws16;                       // [128][32][32][128]
    _Float16* F32  = ws16 + 16777216;
    _Float16* S32  = ws16 + 2 * 16777216;
    _Float16* A16  = ws16 + 3 * 16777216;        // [128][16][16][128]
    _Float16* F16b = A16 + 4194304;
    _Float16* S16b = A16 + 2 * 4194304;
    _Float16* Wb   = A16 + 3 * 4194304;          // 8 layers x [9][128][128]
    float* stats = (float*)(Wb + 8 * 147456);
    float* scsh  = stats + 256;
    float* gm    = scsh + 256;

    zero_stats<<<1, 256, 0, stream>>>(stats);
    conv1_stats2<<<512, 256, 0, stream>>>(x, w1, b1, stats);
    bn_finalize<<<1, 128, 0, stream>>>(stats, bng, bnb, scsh);
    conv1_pool<<<256, 256, 0, stream>>>(x, w1, b1, scsh, A32);

    const float* lw[8] = {fw[0], rw[0], fw[1], rw[1], fw[2], rw[2], fw[3], rw[3]};
    for (int i = 0; i < 8; ++i)
        wcvt<<<576, 256, 0, stream>>>(lw[i], Wb + i * 147456);

    for (int s = 0; s < 2; ++s) {
        conv3<32, false><<<512, 256, 0, stream>>>(A32, Wb + (2*s) * 147456, fb[s], nullptr, F32);
        lrn_k<<<512, 256, 0, stream>>>(F32, A32);
        for (int it = 0; it < 3; ++it) {
            conv3<32, true><<<512, 256, 0, stream>>>(A32, Wb + (2*s+1) * 147456, nullptr, F32, S32);
            lrn_k<<<512, 256, 0, stream>>>(S32, A32);
        }
    }
    pool32<<<16384, 256, 0, stream>>>(A32, A16);
    for (int s = 2; s < 4; ++s) {
        conv3<16, false><<<256, 256, 0, stream>>>(A16, Wb + (2*s) * 147456, fb[s], nullptr, F16b);
        lrn_k<<<128, 256, 0, stream>>>(F16b, A16);
        for (int it = 0; it < 3; ++it) {
            conv3<16, true><<<256, 256, 0, stream>>>(A16, Wb + (2*s+1) * 147456, nullptr, F16b, S16b);
            lrn_k<<<128, 256, 0, stream>>>(S16b, A16);
        }
    }
    gmax_k<<<64, 256, 0, stream>>>(A16, gm);
    mlp_k<<<5, 256, 0, stream>>>(gm, mw, mb, out);
}